// Round 2
// baseline (316.867 us; speedup 1.0000x reference)
//
#include <hip/hip_runtime.h>
#include <stdint.h>

// ---------------------------------------------------------------------------
// AudioVisualModel fused loss on MI355X — R2: no-LDS streaming MFMA.
// B=16, Na=128, T=10, Nv=196, D=256.
// prep:  normalize -> bf16; visual padded per-t to 208 rows (zeros in pad).
// main:  512 blocks = (x, y, t-half). 8 waves x 16 audio rows in regs.
//        Visual frags streamed global->VGPR (L1/L2-resident), reg double-buffer.
//        Per-(row,t) max + nonneg sum fully in-register; no atomics.
// final: 16x16 InfoNCE + reg terms.
// ---------------------------------------------------------------------------

typedef __bf16 bf16x8 __attribute__((ext_vector_type(8)));
typedef float  f32x4  __attribute__((ext_vector_type(4)));

// workspace layout (bytes)
#define WS_A_OFF    ((size_t)0)                         // a_n: 2048 x 256 bf16 = 1 MB
#define WS_V_OFF    ((size_t)(1u<<20))                  // v_pad: 16 x 2112 x 512 B = 16.5 MB
#define WS_PART_OFF (WS_V_OFF + (size_t)16*2112*512)    // clip parts [512] + nn parts [512]

__device__ __forceinline__ unsigned short f2bf(float f) {
    unsigned b = __float_as_uint(f);
    return (unsigned short)((b + 0x7fffu + ((b >> 16) & 1u)) >> 16);   // RNE
}

// ---------------------------------------------------------------------------
// prep: one wave per output row. rows [0,2048): audio; [2048, 2048+16*2112): visual.
// visual padded row layout per y: t*208 + v, v in [196,208) zeroed.
__global__ __launch_bounds__(512) void prep_kernel(const float* __restrict__ audio,
                                                   const float* __restrict__ visual,
                                                   char* __restrict__ ws)
{
    const int wrow = blockIdx.x * 8 + (threadIdx.x >> 6);
    const int lane = threadIdx.x & 63;
    if (wrow < 2048) {
        const float4 v = *(const float4*)(audio + (size_t)wrow * 256 + lane * 4);
        float ss = v.x*v.x + v.y*v.y + v.z*v.z + v.w*v.w;
        #pragma unroll
        for (int m = 1; m < 64; m <<= 1) ss += __shfl_xor(ss, m);
        const float sc = 1.0f / fmaxf(sqrtf(ss), 1e-12f);
        ushort4 o;
        o.x = f2bf(v.x*sc); o.y = f2bf(v.y*sc); o.z = f2bf(v.z*sc); o.w = f2bf(v.w*sc);
        *(ushort4*)(ws + WS_A_OFF + (size_t)wrow * 512 + lane * 8) = o;
    } else {
        const int vr  = wrow - 2048;          // global padded visual row
        const int y   = vr / 2112;
        const int rem = vr % 2112;
        const int t   = rem / 208;
        const int v   = rem % 208;
        ushort4 o = make_ushort4(0, 0, 0, 0);
        if (t < 10 && v < 196) {
            const float4 f = *(const float4*)(visual + (size_t)((y*10 + t)*196 + v) * 256 + lane * 4);
            float ss = f.x*f.x + f.y*f.y + f.z*f.z + f.w*f.w;
            #pragma unroll
            for (int m = 1; m < 64; m <<= 1) ss += __shfl_xor(ss, m);
            const float sc = 1.0f / fmaxf(sqrtf(ss), 1e-12f);
            o.x = f2bf(f.x*sc); o.y = f2bf(f.y*sc); o.z = f2bf(f.z*sc); o.w = f2bf(f.w*sc);
        }
        *(ushort4*)(ws + WS_V_OFF + (size_t)vr * 512 + lane * 8) = o;
    }
}

// ---------------------------------------------------------------------------
// main: 512 blocks. b -> (xcd = b&7) owns y-panels {2*xcd, 2*xcd+1} (L2 locality).
// Each block: pair (x,y), t-half h (frags [h*65, h*65+65), 13 frags per t).
// Wave wid owns audio rows [x*128 + wid*16, +16). All waves share the visual
// frag stream; raw s_barrier per frag keeps them converged for L1 sharing.
__global__ __launch_bounds__(512, 4) void main_kernel(char* __restrict__ ws)
{
    __shared__ float red[16];
    const int tid  = threadIdx.x;
    const int lane = tid & 63;
    const int wid  = tid >> 6;
    const int l15  = lane & 15;
    const int kg   = lane >> 4;

    const int b = blockIdx.x;
    const int xcd = b & 7, s = b >> 3;       // s in [0,64)
    const int y = xcd * 2 + (s >> 5);
    const int x = (s >> 1) & 15;
    const int h = s & 1;

    // audio fragments -> registers (L2-resident, loaded once)
    bf16x8 af[8];
    {
        const char* ab = ws + WS_A_OFF + (size_t)(x*128 + wid*16) * 512;
        #pragma unroll
        for (int k = 0; k < 8; ++k) {
            uint4 u = *(const uint4*)(ab + l15*512 + k*64 + kg*16);
            af[k] = __builtin_bit_cast(bf16x8, u);
        }
    }

    const char* vsrc = ws + WS_V_OFF + (size_t)y * (2112*512) + (size_t)h * (65*8192);
    const int voff = l15*512 + kg*16;

    float tsum = 0.f, nn = 0.f, rmax = -3.4e38f;

    auto process = [&](const uint4* vf, int lf) {
        f32x4 acc = {0.f, 0.f, 0.f, 0.f};
        #pragma unroll
        for (int k = 0; k < 8; ++k)
            acc = __builtin_amdgcn_mfma_f32_16x16x32_bf16(
                __builtin_bit_cast(bf16x8, vf[k]), af[k], acc, 0, 0, 0);
        const int fm = lf % 13;                       // wave-uniform
        float m = fmaxf(fmaxf(acc[0], acc[1]), fmaxf(acc[2], acc[3]));
        #pragma unroll
        for (int i = 0; i < 4; ++i) {
            const float g = fminf(acc[i], 0.f);
            nn = fmaf(g, g, nn);
        }
        if (fm == 12) {
            // last frag of this t: only visual rows [192,196) valid -> kg==0
            if (kg != 0) m = -3.4e38f;
            rmax = fmaxf(rmax, m);
            float v = fmaxf(rmax, __shfl_xor(rmax, 16));
            v = fmaxf(v, __shfl_xor(v, 32));
            tsum += v;                                 // duplicated over kg; /4 later
            rmax = -3.4e38f;
        } else {
            rmax = fmaxf(rmax, m);
        }
    };

    uint4 vfA[8], vfB[8];
    #pragma unroll
    for (int k = 0; k < 8; ++k) vfA[k] = *(const uint4*)(vsrc + voff + k*64);

    for (int p = 0; p < 32; ++p) {
        {   // issue loads for frag 2p+1 (no wait)
            const char* sp = vsrc + (size_t)(2*p + 1) * 8192 + voff;
            #pragma unroll
            for (int k = 0; k < 8; ++k) vfB[k] = *(const uint4*)(sp + k*64);
        }
        __builtin_amdgcn_s_barrier();      // convergence only; no data dep
        process(vfA, 2*p);
        {   // issue loads for frag 2p+2 (frag 66 prefetch at p=31 stays in-bounds)
            const char* sp = vsrc + (size_t)(2*p + 2) * 8192 + voff;
            #pragma unroll
            for (int k = 0; k < 8; ++k) vfA[k] = *(const uint4*)(sp + k*64);
        }
        __builtin_amdgcn_s_barrier();
        process(vfB, 2*p + 1);
    }
    process(vfA, 64);                       // frag 64: fm==12 -> final flush

    // block reduction: tsum duplicated x4 over kg -> scale 0.25 at write
    #pragma unroll
    for (int m2 = 1; m2 < 64; m2 <<= 1) {
        tsum += __shfl_xor(tsum, m2);
        nn   += __shfl_xor(nn, m2);
    }
    if (lane == 0) { red[wid] = tsum; red[8 + wid] = nn; }
    __syncthreads();
    if (tid == 0) {
        float S = 0.f, N = 0.f;
        #pragma unroll
        for (int w = 0; w < 8; ++w) { S += red[w]; N += red[8 + w]; }
        float* cp = (float*)(ws + WS_PART_OFF);
        cp[(x*16 + y)*2 + h]       = S * 0.25f;
        cp[512 + (x*16 + y)*2 + h] = N;
    }
}

// ---------------------------------------------------------------------------
// final: 16x16 InfoNCE + regularizers -> 3 scalars
__global__ void final_kernel(const char* __restrict__ ws,
                             const float* __restrict__ temp,
                             float* __restrict__ out)
{
    __shared__ float cs[16][17];
    __shared__ float nnred[256];
    __shared__ float lse_r[16], lse_c[16];
    const int tid = threadIdx.x;
    const float T = temp[0];
    const float* cp = (const float*)(ws + WS_PART_OFF);
    cs[tid >> 4][tid & 15] = (cp[tid*2] + cp[tid*2 + 1]) / (1280.0f * T);
    nnred[tid] = cp[512 + tid*2] + cp[512 + tid*2 + 1];
    __syncthreads();
    for (int s = 128; s > 0; s >>= 1) {
        if (tid < s) nnred[tid] += nnred[tid + s];
        __syncthreads();
    }
    if (tid < 16) {
        float m = -3.4e38f;
        for (int j = 0; j < 16; ++j) m = fmaxf(m, cs[tid][j]);
        float s = 0.f;
        for (int j = 0; j < 16; ++j) s += expf(cs[tid][j] - m);
        lse_r[tid] = m + logf(s);
    } else if (tid < 32) {
        const int c = tid - 16;
        float m = -3.4e38f;
        for (int j = 0; j < 16; ++j) m = fmaxf(m, cs[j][c]);
        float s = 0.f;
        for (int j = 0; j < 16; ++j) s += expf(cs[j][c] - m);
        lse_c[c] = m + logf(s);
    }
    __syncthreads();
    if (tid == 0) {
        float acc = 0.f;
        for (int i = 0; i < 16; ++i)
            acc += (lse_r[i] - cs[i][i]) + (lse_c[i] - cs[i][i]);
        const float contrastive = 0.5f * acc * (1.0f / 16.0f);
        const float l_nonneg = nnred[0] / (64225280.0f * T * T);
        const float lt = logf(T);
        float tl = fmaxf(-lt, 0.f); tl = tl * tl; tl = tl * tl;
        float th = fmaxf(lt - 1.0986122886681098f, 0.f); th = th * th; th = th * th;
        const float reg = l_nonneg + tl + th;
        out[0] = contrastive + 0.3f * reg;
        out[1] = contrastive;
        out[2] = reg;
    }
}

// ---------------------------------------------------------------------------
extern "C" void kernel_launch(void* const* d_in, const int* in_sizes, int n_in,
                              void* d_out, int out_size, void* d_ws, size_t ws_size,
                              hipStream_t stream)
{
    const float* audio  = (const float*)d_in[0];
    const float* visual = (const float*)d_in[1];
    const float* temp   = (const float*)d_in[2];
    char* ws = (char*)d_ws;

    prep_kernel<<<4480, 512, 0, stream>>>(audio, visual, ws);   // 35840 rows / 8 waves
    main_kernel<<<512, 512, 0, stream>>>(ws);                   // (x, y, t-half)
    final_kernel<<<1, 256, 0, stream>>>(ws, temp, (float*)d_out);
}

// Round 3
// 126.695 us; speedup vs baseline: 2.5010x; 2.5010x over previous
//
#include <hip/hip_runtime.h>
#include <stdint.h>

// ---------------------------------------------------------------------------
// AudioVisualModel fused loss on MI355X — R3: LDS-staged MFMA, counted vmcnt.
// B=16, Na=128, T=10, Nv=196, D=256.
// prep:  normalize -> bf16; visual padded per-t to 208 rows, panel padded to
//        2176 rows; rows pre-swizzled (16B-unit XOR row&7) for conflict-free
//        ds_read_b128 after linear global_load_lds staging.
// main:  512 blocks = (x, y, t-half: 5 t's / 65 frags each). 8 waves =
//        4 audio-quarters x 2 visual-slots. af[2][8] in regs (64 VGPR).
//        Visual chunks (4 frags, 32KB) double-buffered via global_load_lds;
//        raw s_barrier + counted s_waitcnt vmcnt(4) (no full drain).
//        Per-(row,t) max via LDS atomicMax (int-encoded floats).
// final: 16x16 InfoNCE + reg terms.
// ---------------------------------------------------------------------------

typedef __bf16 bf16x8 __attribute__((ext_vector_type(8)));
typedef float  f32x4  __attribute__((ext_vector_type(4)));

#define P_ROWS 2176   // padded rows per visual panel (>= 2*1040 + chunk overrun)

#define WS_A_OFF  ((size_t)0)                        // 2048 x 512B = 1 MB
#define WS_V_OFF  ((size_t)(1u<<20))                 // 16 x 2176 x 512B = 17.4 MB
#define WS_CP_OFF (WS_V_OFF + (size_t)16*P_ROWS*512) // clip parts [512] + nn [512]

__device__ __forceinline__ unsigned short f2bf(float f) {
    unsigned b = __float_as_uint(f);
    return (unsigned short)((b + 0x7fffu + ((b >> 16) & 1u)) >> 16);   // RNE
}
// order-preserving float<->int encoding for integer atomicMax
__device__ __forceinline__ int fenc(float f) {
    int i = __float_as_int(f);
    return i >= 0 ? i : (i ^ 0x7fffffff);
}
__device__ __forceinline__ float fdec(int i) {
    return __int_as_float(i >= 0 ? i : (i ^ 0x7fffffff));
}
__device__ __forceinline__ void gld_lds16(const char* g, char* l) {
    __builtin_amdgcn_global_load_lds(
        (const __attribute__((address_space(1))) void*)g,
        (__attribute__((address_space(3))) void*)l, 16, 0, 0);
}

// ---------------------------------------------------------------------------
// prep: one wave per output row. rows [0,2048): audio (linear layout);
// [2048, 2048+16*2176): visual (padded, swizzled).
__global__ __launch_bounds__(512) void prep_kernel(const float* __restrict__ audio,
                                                   const float* __restrict__ visual,
                                                   char* __restrict__ ws)
{
    const int wrow = blockIdx.x * 8 + (threadIdx.x >> 6);
    const int lane = threadIdx.x & 63;
    if (wrow < 2048) {
        const float4 v = *(const float4*)(audio + (size_t)wrow * 256 + lane * 4);
        float ss = v.x*v.x + v.y*v.y + v.z*v.z + v.w*v.w;
        #pragma unroll
        for (int m = 1; m < 64; m <<= 1) ss += __shfl_xor(ss, m);
        const float sc = 1.0f / fmaxf(sqrtf(ss), 1e-12f);
        ushort4 o;
        o.x = f2bf(v.x*sc); o.y = f2bf(v.y*sc); o.z = f2bf(v.z*sc); o.w = f2bf(v.w*sc);
        *(ushort4*)(ws + WS_A_OFF + (size_t)wrow * 512 + lane * 8) = o;
    } else {
        const int vr  = wrow - 2048;          // padded visual row [0, 16*2176)
        const int y   = vr / P_ROWS;
        const int rem = vr % P_ROWS;
        const int t   = rem / 208;
        const int v   = rem % 208;
        ushort4 o = make_ushort4(0, 0, 0, 0);
        if (t < 10 && v < 196) {
            const float4 f = *(const float4*)(visual + (size_t)((y*10 + t)*196 + v) * 256 + lane * 4);
            float ss = f.x*f.x + f.y*f.y + f.z*f.z + f.w*f.w;
            #pragma unroll
            for (int m = 1; m < 64; m <<= 1) ss += __shfl_xor(ss, m);
            const float sc = 1.0f / fmaxf(sqrtf(ss), 1e-12f);
            o.x = f2bf(f.x*sc); o.y = f2bf(f.y*sc); o.z = f2bf(f.z*sc); o.w = f2bf(f.w*sc);
        }
        const int u   = lane >> 1;                 // 16B unit within 512B row
        const int swz = u ^ (vr & 7);
        *(ushort4*)(ws + WS_V_OFF + (size_t)vr * 512 + (swz << 4) + ((lane & 1) << 3)) = o;
    }
}

// ---------------------------------------------------------------------------
#define STAGE(c_, buf_) do {                                        \
    const char* s_ = vbase + (size_t)(c_) * 32768 + tid * 16;       \
    char* d_ = &smem[buf_][0] + tid * 16;                           \
    gld_lds16(s_,         d_);                                      \
    gld_lds16(s_ +  8192, d_ +  8192);                              \
    gld_lds16(s_ + 16384, d_ + 16384);                              \
    gld_lds16(s_ + 24576, d_ + 24576);                              \
} while (0)

__global__ __launch_bounds__(512, 4) void main_kernel(char* __restrict__ ws)
{
    __shared__ __align__(16) char smem[2][32768];
    __shared__ int part_lds[640];        // [128 rows][5 t], int-encoded max
    __shared__ float red[16];

    const int tid  = threadIdx.x;
    const int lane = tid & 63;
    const int wid  = tid >> 6;
    const int l15  = lane & 15;
    const int kg   = lane >> 4;
    const int aw   = wid & 3;            // audio quarter (32 rows)
    const int vw   = wid >> 2;           // visual slot (frags 2vw,2vw+1 of chunk)

    const int b = blockIdx.x;
    const int xcd = b & 7, s = b >> 3;   // s in [0,64)
    const int y = xcd * 2 + (s >> 5);    // each XCD owns 2 y-panels (L2-resident)
    const int x = (s >> 1) & 15;
    const int h = s & 1;                 // t-half: t in [5h, 5h+5)

    part_lds[tid] = (int)0x80000000;
    if (tid < 128) part_lds[512 + tid] = (int)0x80000000;

    // audio fragments -> registers (64 VGPR), force completion before staging
    bf16x8 af[2][8];
    {
        const char* ab = ws + WS_A_OFF + (size_t)(x*128 + aw*32) * 512;
        #pragma unroll
        for (int j = 0; j < 2; ++j)
            #pragma unroll
            for (int k = 0; k < 8; ++k) {
                uint4 u = *(const uint4*)(ab + (j*16 + l15)*512 + k*64 + kg*16);
                af[j][k] = __builtin_bit_cast(bf16x8, u);
            }
    }
    asm volatile("s_waitcnt vmcnt(0)" ::: "memory");

    const char* vbase = ws + WS_V_OFF + ((size_t)y * P_ROWS + (size_t)h * 1040) * 512;

    float nn = 0.f;
    float rmax0 = -3.4e38f, rmax1 = -3.4e38f;

    STAGE(0, 0);                         // prologue
    __builtin_amdgcn_s_barrier();        // part_lds init + stage(0) issued

    int cur = 0;
    for (int c = 0; c < 17; ++c) {
        if (c < 16) {
            STAGE(c + 1, cur ^ 1);
            asm volatile("s_waitcnt vmcnt(4)" ::: "memory");  // stage(c) done; c+1 in flight
        } else {
            asm volatile("s_waitcnt vmcnt(0)" ::: "memory");
        }
        __builtin_amdgcn_s_barrier();

        #pragma unroll
        for (int q2 = 0; q2 < 2; ++q2) {
            const int f = 4*c + 2*vw + q2;          // frag index within half [0,68)
            if (f < 65) {
                const int qq = 2*vw + q2;           // frag within chunk
                const char* bb = &smem[cur][0] + (qq*16 + l15) * 512;
                const int sw = (l15 & 7) << 4;      // read-side XOR (row&7 == l15&7)

                f32x4 acc0 = {0.f,0.f,0.f,0.f}, acc1 = {0.f,0.f,0.f,0.f};
                bf16x8 vf[4];
                #pragma unroll
                for (int k = 0; k < 4; ++k) {
                    uint4 q = *(const uint4*)(bb + ((((k*4 + kg) << 4)) ^ sw));
                    vf[k] = __builtin_bit_cast(bf16x8, q);
                }
                #pragma unroll
                for (int k = 0; k < 4; ++k) {
                    acc0 = __builtin_amdgcn_mfma_f32_16x16x32_bf16(vf[k], af[0][k], acc0, 0,0,0);
                    acc1 = __builtin_amdgcn_mfma_f32_16x16x32_bf16(vf[k], af[1][k], acc1, 0,0,0);
                }
                #pragma unroll
                for (int k = 0; k < 4; ++k) {
                    uint4 q = *(const uint4*)(bb + (((k*4 + 16 + kg) << 4) ^ sw));
                    vf[k] = __builtin_bit_cast(bf16x8, q);
                }
                #pragma unroll
                for (int k = 0; k < 4; ++k) {
                    acc0 = __builtin_amdgcn_mfma_f32_16x16x32_bf16(vf[k], af[0][k+4], acc0, 0,0,0);
                    acc1 = __builtin_amdgcn_mfma_f32_16x16x32_bf16(vf[k], af[1][k+4], acc1, 0,0,0);
                }

                const int t  = f / 13;              // wave-uniform, magic-mul
                const int ft = f - t*13;
                float m0 = fmaxf(fmaxf(acc0[0], acc0[1]), fmaxf(acc0[2], acc0[3]));
                float m1 = fmaxf(fmaxf(acc1[0], acc1[1]), fmaxf(acc1[2], acc1[3]));
                #pragma unroll
                for (int i = 0; i < 4; ++i) {
                    const float g0 = fminf(acc0[i], 0.f);
                    const float g1 = fminf(acc1[i], 0.f);
                    nn = fmaf(g0, g0, nn);
                    nn = fmaf(g1, g1, nn);
                }
                if (ft == 12 && kg != 0) { m0 = -3.4e38f; m1 = -3.4e38f; }  // visual pad rows
                rmax0 = fmaxf(rmax0, m0);
                rmax1 = fmaxf(rmax1, m1);

                const int fn = q2 ? f + 3 : f + 1;  // this wave's next frag
                const int tn = (fn < 65) ? fn / 13 : 5;
                if (tn != t) {                       // last frag of t for this wave
                    float v0 = fmaxf(rmax0, __shfl_xor(rmax0, 16));
                    v0 = fmaxf(v0, __shfl_xor(v0, 32));
                    float v1 = fmaxf(rmax1, __shfl_xor(rmax1, 16));
                    v1 = fmaxf(v1, __shfl_xor(v1, 32));
                    if (lane < 16) {
                        atomicMax(&part_lds[(aw*32 + l15) * 5 + t],      fenc(v0));
                        atomicMax(&part_lds[(aw*32 + 16 + l15) * 5 + t], fenc(v1));
                    }
                    rmax0 = -3.4e38f;
                    rmax1 = -3.4e38f;
                }
            }
        }
        asm volatile("" ::: "memory");
        __builtin_amdgcn_s_barrier();    // reads of buf[cur] done before restage
        cur ^= 1;
    }

    __syncthreads();                     // drain LDS atomics, full visibility

    float sum = 0.f;
    for (int i = tid; i < 640; i += 512) sum += fdec(part_lds[i]);
    #pragma unroll
    for (int m = 32; m >= 1; m >>= 1) {
        sum += __shfl_xor(sum, m);
        nn  += __shfl_xor(nn, m);
    }
    if (lane == 0) { red[wid] = sum; red[8 + wid] = nn; }
    __syncthreads();
    if (tid == 0) {
        float S = 0.f, N = 0.f;
        #pragma unroll
        for (int w = 0; w < 8; ++w) { S += red[w]; N += red[8 + w]; }
        float* cp = (float*)(ws + WS_CP_OFF);
        cp[(x*16 + y)*2 + h]       = S;
        cp[512 + (x*16 + y)*2 + h] = N;
    }
}

// ---------------------------------------------------------------------------
// final: 16x16 InfoNCE + regularizers -> 3 scalars
__global__ void final_kernel(const char* __restrict__ ws,
                             const float* __restrict__ temp,
                             float* __restrict__ out)
{
    __shared__ float cs[16][17];
    __shared__ float nnred[256];
    __shared__ float lse_r[16], lse_c[16];
    const int tid = threadIdx.x;
    const float T = temp[0];
    const float* cp = (const float*)(ws + WS_CP_OFF);
    cs[tid >> 4][tid & 15] = (cp[tid*2] + cp[tid*2 + 1]) / (1280.0f * T);
    nnred[tid] = cp[512 + tid*2] + cp[512 + tid*2 + 1];
    __syncthreads();
    for (int s = 128; s > 0; s >>= 1) {
        if (tid < s) nnred[tid] += nnred[tid + s];
        __syncthreads();
    }
    if (tid < 16) {
        float m = -3.4e38f;
        for (int j = 0; j < 16; ++j) m = fmaxf(m, cs[tid][j]);
        float s = 0.f;
        for (int j = 0; j < 16; ++j) s += expf(cs[tid][j] - m);
        lse_r[tid] = m + logf(s);
    } else if (tid < 32) {
        const int c = tid - 16;
        float m = -3.4e38f;
        for (int j = 0; j < 16; ++j) m = fmaxf(m, cs[j][c]);
        float s = 0.f;
        for (int j = 0; j < 16; ++j) s += expf(cs[j][c] - m);
        lse_c[c] = m + logf(s);
    }
    __syncthreads();
    if (tid == 0) {
        float acc = 0.f;
        for (int i = 0; i < 16; ++i)
            acc += (lse_r[i] - cs[i][i]) + (lse_c[i] - cs[i][i]);
        const float contrastive = 0.5f * acc * (1.0f / 16.0f);
        const float l_nonneg = nnred[0] / (64225280.0f * T * T);
        const float lt = logf(T);
        float tl = fmaxf(-lt, 0.f); tl = tl * tl; tl = tl * tl;
        float th = fmaxf(lt - 1.0986122886681098f, 0.f); th = th * th; th = th * th;
        const float reg = l_nonneg + tl + th;
        out[0] = contrastive + 0.3f * reg;
        out[1] = contrastive;
        out[2] = reg;
    }
}

// ---------------------------------------------------------------------------
extern "C" void kernel_launch(void* const* d_in, const int* in_sizes, int n_in,
                              void* d_out, int out_size, void* d_ws, size_t ws_size,
                              hipStream_t stream)
{
    const float* audio  = (const float*)d_in[0];
    const float* visual = (const float*)d_in[1];
    const float* temp   = (const float*)d_in[2];
    char* ws = (char*)d_ws;

    prep_kernel<<<4608, 512, 0, stream>>>(audio, visual, ws);   // 36864 rows / 8 waves
    main_kernel<<<512, 512, 0, stream>>>(ws);                   // (x, y, t-half)
    final_kernel<<<1, 256, 0, stream>>>(ws, temp, (float*)d_out);
}